// Round 1
// baseline (2666.126 us; speedup 1.0000x reference)
//
#include <hip/hip_runtime.h>

// ChildSumTreeLSTM on a static 4-ary heap tree.
// N=8192, H=256, D=300, K=4, OUT=4. Leaves = 2048..8191. Internal 0..2047 in 7 levels.
// Workspace (50.3 MB, unchanged layout):
//   gx : [8192][1024] f32   (gate order i,f,o,u)
//   Hb : [8192][256]  f32
//   Cb : [8192][256]  f32
// D (level-GEMM output, <=7.3 MB) aliases gx rows 2048.. (dead after leaf phase).
// Grid-barrier counters live in gx row 8191 cols 256..511 (leaf f-gate cols:
// written-but-never-read region; gx_gemm skips those tiles and inits the bar).

#define N_NODES 8192
#define HDIM 256
#define DDIM 300
#define GXC 1024
#define LEAF_FIRST 2048
#define WH_STRIDE 65536   // 256*256
#define NBLK 512          // persistent tree kernel: 2 blocks/CU on 256 CUs

__device__ __forceinline__ float sigf(float x) { return 1.0f / (1.0f + __expf(-x)); }

// ---------------- grid-wide barrier (sense-reversing generation) ------------
// All NBLK blocks are co-resident (__launch_bounds__(256,2), 512 blocks,
// 256 CUs, ~8.7KB LDS, modest VGPR -> capacity >= 4 blocks/CU).
__device__ __forceinline__ void gsync(unsigned* cnt, unsigned* gen)
{
    __syncthreads();          // all waves' vmem drained (vmcnt(0) at barrier)
    __threadfence();          // agent-scope release (L2 writeback)
    if (threadIdx.x == 0) {
        unsigned g = __hip_atomic_load(gen, __ATOMIC_RELAXED, __HIP_MEMORY_SCOPE_AGENT);
        unsigned a = __hip_atomic_fetch_add(cnt, 1u, __ATOMIC_ACQ_REL, __HIP_MEMORY_SCOPE_AGENT);
        if (a == NBLK - 1u) {
            __hip_atomic_store(cnt, 0u, __ATOMIC_RELAXED, __HIP_MEMORY_SCOPE_AGENT);
            __hip_atomic_fetch_add(gen, 1u, __ATOMIC_ACQ_REL, __HIP_MEMORY_SCOPE_AGENT);
        } else {
            while (__hip_atomic_load(gen, __ATOMIC_ACQUIRE, __HIP_MEMORY_SCOPE_AGENT) == g)
                __builtin_amdgcn_s_sleep(1);
        }
    }
    __syncthreads();
    __threadfence();          // agent-scope acquire (L1/L2 invalidate)
}

// ---------- Kernel 1: gx[n][c] = emb[xs[n]] · Wx[c] + bx[c]  (64x64 tile) ----
__global__ __launch_bounds__(256) void gx_gemm(
    const int* __restrict__ xs, const float* __restrict__ emb,
    const float* __restrict__ Wx, const float* __restrict__ bx,
    float* __restrict__ gx, unsigned* __restrict__ bar)
{
    // Init the tree kernel's barrier (runs before tree_kernel in stream order;
    // block (0,0) writes rows 0..63 cols 0..63, never the bar region).
    if (blockIdx.x == 0 && blockIdx.y == 0 && threadIdx.x == 0) {
        bar[0]   = 0u;   // cnt
        bar[128] = 0u;   // gen (separate 128B lines)
    }

    const int n0 = blockIdx.y * 64;
    const int c0 = blockIdx.x * 64;
    // Leaf rows' f-gate columns (256..511) are never read downstream: skip.
    if (n0 >= LEAF_FIRST && c0 >= 256 && c0 < 512) return;

    __shared__ __align__(16) float As[16][68];
    __shared__ __align__(16) float Bs[16][68];
    const int tid  = threadIdx.x;
    const int sr   = tid >> 2;
    const int sk   = (tid & 3) << 2;
    const int trow = (tid >> 4) << 2;
    const int tcol = (tid & 15) << 2;

    const long arow = (long)xs[n0 + sr] * DDIM;
    const long brow = (long)(c0 + sr) * DDIM;

    float acc[4][4] = {};

    for (int k0 = 0; k0 < DDIM; k0 += 16) {
        float4 av, bv;
        if (k0 + sk < DDIM) {
            av = *(const float4*)(emb + arow + k0 + sk);
            bv = *(const float4*)(Wx  + brow + k0 + sk);
        } else {
            av = make_float4(0.f, 0.f, 0.f, 0.f);
            bv = make_float4(0.f, 0.f, 0.f, 0.f);
        }
        __syncthreads();
        As[sk+0][sr] = av.x; As[sk+1][sr] = av.y; As[sk+2][sr] = av.z; As[sk+3][sr] = av.w;
        Bs[sk+0][sr] = bv.x; Bs[sk+1][sr] = bv.y; Bs[sk+2][sr] = bv.z; Bs[sk+3][sr] = bv.w;
        __syncthreads();
        #pragma unroll
        for (int k = 0; k < 16; k++) {
            float4 a = *(const float4*)&As[k][trow];
            float4 b = *(const float4*)&Bs[k][tcol];
            float avv[4] = {a.x, a.y, a.z, a.w};
            float bvv[4] = {b.x, b.y, b.z, b.w};
            #pragma unroll
            for (int i = 0; i < 4; i++)
                #pragma unroll
                for (int j = 0; j < 4; j++)
                    acc[i][j] = fmaf(avv[i], bvv[j], acc[i][j]);
        }
    }

    #pragma unroll
    for (int i = 0; i < 4; i++) {
        const int col = c0 + tcol;
        float4 r;
        r.x = acc[i][0] + bx[col + 0];
        r.y = acc[i][1] + bx[col + 1];
        r.z = acc[i][2] + bx[col + 2];
        r.w = acc[i][3] + bx[col + 3];
        *(float4*)(gx + (long)(n0 + trow + i) * GXC + col) = r;
    }
}

// ---------- device fn: one 64x64 level-GEMM tile ----------------------------
// tile t decodes to (sec, row-tile, col-tile); sec: 0=i 1=o 2=u 3..6=f child
__device__ void gemm_tile(int t, int ct, int first, int M,
                          const float* __restrict__ Hb,
                          const int* __restrict__ child_idx,
                          const float* __restrict__ child_mask,
                          const float* __restrict__ Wh, float* __restrict__ D,
                          float (*Xs)[68], float (*Ws)[68])
{
    const int tid  = threadIdx.x;
    const int sec  = t / (4 * ct);
    const int rem  = t - sec * 4 * ct;
    const int r0   = (rem / ct) * 64;
    const int c0   = (rem % ct) * 64;
    const int sr   = tid >> 2;
    const int sk   = (tid & 3) << 2;
    const int trow = (tid >> 4) << 2;
    const int tcol = (tid & 15) << 2;

    const float* Wg;
    if      (sec == 0) Wg = Wh;                  // i
    else if (sec == 1) Wg = Wh + 2 * WH_STRIDE;  // o
    else if (sec == 2) Wg = Wh + 3 * WH_STRIDE;  // u
    else               Wg = Wh + 1 * WH_STRIDE;  // f

    const int  nl    = c0 + sr;
    const bool valid = nl < M;
    int   ci[4];
    float cm[4] = {0.f, 0.f, 0.f, 0.f};
    if (valid) {
        const int n = first + nl;
        if (sec < 3) {
            #pragma unroll
            for (int k = 0; k < 4; k++) {
                ci[k] = child_idx[n * 4 + k];
                cm[k] = child_mask[n * 4 + k];
            }
        } else {
            ci[0] = child_idx[n * 4 + (sec - 3)];
            cm[0] = child_mask[n * 4 + (sec - 3)];
        }
    }
    const long wrow = (long)(r0 + sr) * HDIM;

    float acc[4][4] = {};

    for (int k0 = 0; k0 < HDIM; k0 += 16) {
        float4 xv = make_float4(0.f, 0.f, 0.f, 0.f);
        if (valid) {
            if (sec < 3) {
                #pragma unroll
                for (int k = 0; k < 4; k++)
                    if (cm[k] != 0.f) {
                        const float4 hv = *(const float4*)(Hb + ci[k] * HDIM + k0 + sk);
                        xv.x += hv.x; xv.y += hv.y; xv.z += hv.z; xv.w += hv.w;
                    }
            } else if (cm[0] != 0.f) {
                xv = *(const float4*)(Hb + ci[0] * HDIM + k0 + sk);
            }
        }
        const float4 wv = *(const float4*)(Wg + wrow + k0 + sk);
        __syncthreads();
        Xs[sk+0][sr] = xv.x; Xs[sk+1][sr] = xv.y; Xs[sk+2][sr] = xv.z; Xs[sk+3][sr] = xv.w;
        Ws[sk+0][sr] = wv.x; Ws[sk+1][sr] = wv.y; Ws[sk+2][sr] = wv.z; Ws[sk+3][sr] = wv.w;
        __syncthreads();
        #pragma unroll
        for (int k = 0; k < 16; k++) {
            float4 a = *(const float4*)&Ws[k][trow];
            float4 b = *(const float4*)&Xs[k][tcol];
            float avv[4] = {a.x, a.y, a.z, a.w};
            float bvv[4] = {b.x, b.y, b.z, b.w};
            #pragma unroll
            for (int i = 0; i < 4; i++)
                #pragma unroll
                for (int j = 0; j < 4; j++)
                    acc[i][j] = fmaf(avv[i], bvv[j], acc[i][j]);
        }
    }

    #pragma unroll
    for (int j = 0; j < 4; j++) {
        const int col = c0 + tcol + j;
        if (col < M) {
            float4 r;
            r.x = acc[0][j]; r.y = acc[1][j]; r.z = acc[2][j]; r.w = acc[3][j];
            *(float4*)(D + ((long)(sec * M + col)) * HDIM + r0 + trow) = r;
        }
    }
}

// ---------- device fn: per-node pointwise combine ---------------------------
__device__ __forceinline__ void pointwise_node(
    int first, int nl, int M, const float* __restrict__ gx,
    const float* __restrict__ D, const int* __restrict__ child_idx,
    const float* __restrict__ child_mask, const float* __restrict__ bh,
    float* __restrict__ Hb, float* __restrict__ Cb)
{
    const int n = first + nl;
    const int t = threadIdx.x;
    const float di  = D[((long)(0 * M + nl)) * HDIM + t];
    const float dO  = D[((long)(1 * M + nl)) * HDIM + t];
    const float du  = D[((long)(2 * M + nl)) * HDIM + t];
    const float* g = gx + (long)n * GXC;
    const float gi  = g[t]       + bh[t]       + di;
    const float gfb = g[256 + t] + bh[256 + t];
    const float go  = g[512 + t] + bh[512 + t] + dO;
    const float gu  = g[768 + t] + bh[768 + t] + du;

    float c = sigf(gi) * tanhf(gu);
    #pragma unroll
    for (int k = 0; k < 4; k++) {
        const float m = child_mask[n * 4 + k];
        if (m != 0.f) {
            const float df = D[((long)((3 + k) * M + nl)) * HDIM + t];
            const float cc = Cb[(long)child_idx[n * 4 + k] * HDIM + t];
            c = fmaf(sigf(gfb + df), cc, c);
        }
    }
    const float h = sigf(go) * tanhf(c);
    Hb[(long)n * HDIM + t] = h;
    Cb[(long)n * HDIM + t] = c;
}

// ---------- Kernel 2: persistent tree kernel (leaves + 7 levels + out) ------
__global__ __launch_bounds__(256, 2) void tree_kernel(
    const float* __restrict__ gx, const float* __restrict__ bh,
    float* __restrict__ Hb, float* __restrict__ Cb,
    const int* __restrict__ child_idx, const float* __restrict__ child_mask,
    const float* __restrict__ Wh, float* __restrict__ D,
    const float* __restrict__ Wout, const float* __restrict__ bout,
    float* __restrict__ out, unsigned* __restrict__ bar)
{
    __shared__ __align__(16) float Xs[16][68];
    __shared__ __align__(16) float Ws[16][68];
    __shared__ float logits[4];
    unsigned* cnt = bar;
    unsigned* gen = bar + 128;

    // ---- leaves: pure elementwise -----------------------------------------
    {
        const int t = threadIdx.x;
        for (int node = LEAF_FIRST + blockIdx.x; node < N_NODES; node += NBLK) {
            const float* g = gx + (long)node * GXC;
            const float gi = g[t]       + bh[t];
            const float go = g[512 + t] + bh[512 + t];
            const float gu = g[768 + t] + bh[768 + t];
            const float c  = sigf(gi) * tanhf(gu);
            const float h  = sigf(go) * tanhf(c);
            Hb[(long)node * HDIM + t] = h;
            Cb[(long)node * HDIM + t] = c;
        }
    }
    gsync(cnt, gen);

    // ---- 7 internal levels: GEMM phase, sync, pointwise phase, sync -------
    // level p: first = (4^(6-p)-1)/3, M = first_{p-1}-first_p (683 at p=0).
    int first = 1365, M = 683;
    for (int p = 0; p < 7; p++) {
        const int ct     = (M + 63) >> 6;
        const int ntiles = 28 * ct;          // 7 secs * 4 row-tiles * ct col-tiles
        for (int t = blockIdx.x; t < ntiles; t += NBLK)
            gemm_tile(t, ct, first, M, Hb, child_idx, child_mask, Wh, D, Xs, Ws);
        gsync(cnt, gen);
        for (int nl = blockIdx.x; nl < M; nl += NBLK)
            pointwise_node(first, nl, M, gx, D, child_idx, child_mask, bh, Hb, Cb);
        gsync(cnt, gen);
        const int nf = (first - 1) >> 2;     // parent level start
        M = first - nf;
        first = nf;
    }

    // ---- root logits + log_softmax (block 0 only) -------------------------
    if (blockIdx.x == 0) {
        const int tid  = threadIdx.x;
        const int o    = tid >> 6;
        const int lane = tid & 63;
        float s = 0.f;
        for (int j = lane; j < HDIM; j += 64)
            s = fmaf(Wout[o * HDIM + j], Hb[j], s);
        #pragma unroll
        for (int off = 32; off > 0; off >>= 1)
            s += __shfl_down(s, off, 64);
        if (lane == 0) logits[o] = s + bout[o];
        __syncthreads();
        if (tid == 0) {
            float m = logits[0];
            #pragma unroll
            for (int i = 1; i < 4; i++) m = fmaxf(m, logits[i]);
            float se = 0.f;
            #pragma unroll
            for (int i = 0; i < 4; i++) se += __expf(logits[i] - m);
            const float lse = m + __logf(se);
            #pragma unroll
            for (int i = 0; i < 4; i++) out[i] = logits[i] - lse;
        }
    }
}

extern "C" void kernel_launch(void* const* d_in, const int* in_sizes, int n_in,
                              void* d_out, int out_size, void* d_ws, size_t ws_size,
                              hipStream_t stream)
{
    const int*   xs         = (const int*)  d_in[0];
    const int*   child_idx  = (const int*)  d_in[1];
    const float* child_mask = (const float*)d_in[2];
    const float* emb        = (const float*)d_in[3];
    const float* Wx         = (const float*)d_in[4];
    const float* bx         = (const float*)d_in[5];
    const float* Wh         = (const float*)d_in[6];
    const float* bh         = (const float*)d_in[7];
    const float* Wout       = (const float*)d_in[8];
    const float* bout       = (const float*)d_in[9];
    float* out = (float*)d_out;

    float* gxb = (float*)d_ws;
    float* Hb  = gxb + (size_t)N_NODES * GXC;
    float* Cb  = Hb  + (size_t)N_NODES * HDIM;
    // D aliases the gx rows of leaf nodes (dead after leaf phase).
    // Max size: 7*1024*256 floats = 7.3 MB; reaches only gx rows 2048..~3840.
    float* Dbuf = gxb + (size_t)LEAF_FIRST * GXC;
    // Barrier counters: gx row 8191, cols 256..511 — leaf f-gate columns,
    // written by nobody (gx_gemm skips those tiles) and read by nobody.
    unsigned* bar = (unsigned*)(gxb + (size_t)(N_NODES - 1) * GXC + 256);

    gx_gemm<<<dim3(GXC / 64, N_NODES / 64), 256, 0, stream>>>(xs, emb, Wx, bx, gxb, bar);
    tree_kernel<<<NBLK, 256, 0, stream>>>(gxb, bh, Hb, Cb, child_idx, child_mask,
                                          Wh, Dbuf, Wout, bout, out, bar);
}

// Round 2
// 419.062 us; speedup vs baseline: 6.3621x; 6.3621x over previous
//
#include <hip/hip_runtime.h>

// ChildSumTreeLSTM on a static 4-ary heap tree.
// N=8192, H=256, D=300, K=4, OUT=4. Leaves = 2048..8191. Internal 0..2047 in 7 levels.
// Workspace: gx [8192][1024] f32, Hb [8192][256] f32, Cb [8192][256] f32.
// Structure: 9 dispatches, no cross-block sync (grid barriers cost ~170us/ea on
// non-coherent XCD L2s — measured round 1).
//   1. gx_gemm   (skips dead leaf-f tiles: rows>=2048, cols 256..511 never read)
//   2. leaf_kernel
//   3-9. level_fused x7 — one block per 2 nodes does GEMVs + pointwise in-LDS;
//        root dispatch also emits logits/log_softmax.

#define N_NODES 8192
#define HDIM 256
#define DDIM 300
#define GXC 1024
#define LEAF_FIRST 2048
#define WH_STRIDE 65536   // 256*256

__device__ __forceinline__ float sigf(float x) { return 1.0f / (1.0f + __expf(-x)); }

// ---------- Kernel 1: gx[n][c] = emb[xs[n]] · Wx[c] + bx[c]  (64x64 tile) ----
__global__ __launch_bounds__(256) void gx_gemm(
    const int* __restrict__ xs, const float* __restrict__ emb,
    const float* __restrict__ Wx, const float* __restrict__ bx,
    float* __restrict__ gx)
{
    const int n0 = blockIdx.y * 64;
    const int c0 = blockIdx.x * 64;
    // Leaf rows' f-gate columns (256..511) are never read downstream: skip.
    if (n0 >= LEAF_FIRST && c0 >= 256 && c0 < 512) return;

    __shared__ __align__(16) float As[16][68];
    __shared__ __align__(16) float Bs[16][68];
    const int tid  = threadIdx.x;
    const int sr   = tid >> 2;
    const int sk   = (tid & 3) << 2;
    const int trow = (tid >> 4) << 2;
    const int tcol = (tid & 15) << 2;

    const long arow = (long)xs[n0 + sr] * DDIM;
    const long brow = (long)(c0 + sr) * DDIM;

    float acc[4][4] = {};

    for (int k0 = 0; k0 < DDIM; k0 += 16) {
        float4 av, bv;
        if (k0 + sk < DDIM) {
            av = *(const float4*)(emb + arow + k0 + sk);
            bv = *(const float4*)(Wx  + brow + k0 + sk);
        } else {
            av = make_float4(0.f, 0.f, 0.f, 0.f);
            bv = make_float4(0.f, 0.f, 0.f, 0.f);
        }
        __syncthreads();
        As[sk+0][sr] = av.x; As[sk+1][sr] = av.y; As[sk+2][sr] = av.z; As[sk+3][sr] = av.w;
        Bs[sk+0][sr] = bv.x; Bs[sk+1][sr] = bv.y; Bs[sk+2][sr] = bv.z; Bs[sk+3][sr] = bv.w;
        __syncthreads();
        #pragma unroll
        for (int k = 0; k < 16; k++) {
            float4 a = *(const float4*)&As[k][trow];
            float4 b = *(const float4*)&Bs[k][tcol];
            float avv[4] = {a.x, a.y, a.z, a.w};
            float bvv[4] = {b.x, b.y, b.z, b.w};
            #pragma unroll
            for (int i = 0; i < 4; i++)
                #pragma unroll
                for (int j = 0; j < 4; j++)
                    acc[i][j] = fmaf(avv[i], bvv[j], acc[i][j]);
        }
    }

    #pragma unroll
    for (int i = 0; i < 4; i++) {
        const int col = c0 + tcol;
        float4 r;
        r.x = acc[i][0] + bx[col + 0];
        r.y = acc[i][1] + bx[col + 1];
        r.z = acc[i][2] + bx[col + 2];
        r.w = acc[i][3] + bx[col + 3];
        *(float4*)(gx + (long)(n0 + trow + i) * GXC + col) = r;
    }
}

// ---------- Kernel 2: leaves — pure elementwise -----------------------------
__global__ __launch_bounds__(256) void leaf_kernel(
    const float* __restrict__ gx, const float* __restrict__ bh,
    float* __restrict__ Hb, float* __restrict__ Cb)
{
    const int node = LEAF_FIRST + blockIdx.x;
    const int t = threadIdx.x;
    const float* g = gx + (long)node * GXC;
    const float gi = g[t]       + bh[t];
    const float go = g[512 + t] + bh[512 + t];
    const float gu = g[768 + t] + bh[768 + t];
    const float c  = sigf(gi) * tanhf(gu);
    const float h  = sigf(go) * tanhf(c);
    Hb[(long)node * HDIM + t] = h;
    Cb[(long)node * HDIM + t] = c;
}

// ---------- Kernel 3: fused per-level kernel --------------------------------
// One block = 2 nodes. 256 threads = 64 quads; quad q owns output row
// r = rb*64+q (rb=0..3), lane j covers k in {16*k4 + 4*j .. +3}.
// Computes 7 GEMVs per node (i,o,u on hs; f on each child h) with Wh rows
// read straight from L2 (Wh = 1MB, L2-resident), reduces within the quad,
// stashes results in LDS, then does the pointwise combine in-block.
// Root dispatch (do_out=1) also computes logits + log_softmax.
__global__ __launch_bounds__(256) void level_fused(
    int first, int M, int do_out,
    const float* __restrict__ gx, const int* __restrict__ child_idx,
    const float* __restrict__ child_mask, const float* __restrict__ Wh,
    const float* __restrict__ bh, float* __restrict__ Hb, float* __restrict__ Cb,
    const float* __restrict__ Wout, const float* __restrict__ bout,
    float* __restrict__ out)
{
    __shared__ __align__(16) float Xs[2][5][HDIM];   // [g][0]=hs, [g][1+ch]=h_child
    __shared__ __align__(16) float Ds[2][7][HDIM];   // GEMV results (i,o,u,f0..f3)
    __shared__ float hroot[HDIM];
    __shared__ float logits[4];

    const int t   = threadIdx.x;
    const int q   = t >> 2;       // quad 0..63
    const int j   = t & 3;        // k-lane within quad
    const int nl0 = blockIdx.x * 2;

    // ---- stage children h (masked) + hs into LDS ---------------------------
    int   ci[2][4];
    float cm[2][4];
    #pragma unroll
    for (int g = 0; g < 2; g++) {
        const int nl = nl0 + g;
        float s = 0.f;
        if (nl < M) {
            const int n = first + nl;
            #pragma unroll
            for (int k = 0; k < 4; k++) {
                ci[g][k] = child_idx[n * 4 + k];
                cm[g][k] = child_mask[n * 4 + k];
                float v = 0.f;
                if (cm[g][k] != 0.f) v = Hb[(long)ci[g][k] * HDIM + t];
                Xs[g][1 + k][t] = v;
                s += v;
            }
        } else {
            #pragma unroll
            for (int k = 0; k < 4; k++) { ci[g][k] = 0; cm[g][k] = 0.f; Xs[g][1 + k][t] = 0.f; }
        }
        Xs[g][0][t] = s;
    }
    __syncthreads();

    // ---- 7 GEMVs, 2 nodes, quad-split K ------------------------------------
    float acc[4][2][7];
    #pragma unroll
    for (int a = 0; a < 4; a++)
        #pragma unroll
        for (int b = 0; b < 2; b++)
            #pragma unroll
            for (int c = 0; c < 7; c++) acc[a][b][c] = 0.f;

    const float* __restrict__ Wi = Wh;                   // gate order in Wh: i,f,o,u
    const float* __restrict__ Wf = Wh + WH_STRIDE;
    const float* __restrict__ Wo = Wh + 2 * WH_STRIDE;
    const float* __restrict__ Wu = Wh + 3 * WH_STRIDE;
    const int kj = j << 2;

    long ro[4];
    #pragma unroll
    for (int rb = 0; rb < 4; rb++) ro[rb] = (long)(rb * 64 + q) * HDIM + kj;

    #pragma unroll 4
    for (int k4 = 0; k4 < 16; k4++) {
        const int kk = (k4 << 4) + kj;
        float4 xsv[2], xcv[2][4];
        #pragma unroll
        for (int g = 0; g < 2; g++) {
            xsv[g] = *(const float4*)&Xs[g][0][kk];
            #pragma unroll
            for (int ch = 0; ch < 4; ch++)
                xcv[g][ch] = *(const float4*)&Xs[g][1 + ch][kk];
        }
        #pragma unroll
        for (int rb = 0; rb < 4; rb++) {
            const long o4 = ro[rb] + (k4 << 4);
            const float4 wi = *(const float4*)(Wi + o4);
            const float4 wo = *(const float4*)(Wo + o4);
            const float4 wu = *(const float4*)(Wu + o4);
            const float4 wf = *(const float4*)(Wf + o4);
            #pragma unroll
            for (int g = 0; g < 2; g++) {
                acc[rb][g][0] += wi.x*xsv[g].x + wi.y*xsv[g].y + wi.z*xsv[g].z + wi.w*xsv[g].w;
                acc[rb][g][1] += wo.x*xsv[g].x + wo.y*xsv[g].y + wo.z*xsv[g].z + wo.w*xsv[g].w;
                acc[rb][g][2] += wu.x*xsv[g].x + wu.y*xsv[g].y + wu.z*xsv[g].z + wu.w*xsv[g].w;
                #pragma unroll
                for (int ch = 0; ch < 4; ch++)
                    acc[rb][g][3 + ch] += wf.x*xcv[g][ch].x + wf.y*xcv[g][ch].y
                                        + wf.z*xcv[g][ch].z + wf.w*xcv[g][ch].w;
            }
        }
    }

    // ---- quad reduce + stash in LDS ----------------------------------------
    #pragma unroll
    for (int rb = 0; rb < 4; rb++)
        #pragma unroll
        for (int g = 0; g < 2; g++)
            #pragma unroll
            for (int s7 = 0; s7 < 7; s7++) {
                float v = acc[rb][g][s7];
                v += __shfl_xor(v, 1, 64);
                v += __shfl_xor(v, 2, 64);
                if (j == 0) Ds[g][s7][rb * 64 + q] = v;
            }
    __syncthreads();

    // ---- pointwise combine -------------------------------------------------
    #pragma unroll
    for (int g = 0; g < 2; g++) {
        const int nl = nl0 + g;
        if (nl < M) {
            const int n = first + nl;
            const float* gg = gx + (long)n * GXC;
            const float gi  = gg[t]       + bh[t]       + Ds[g][0][t];
            const float gfb = gg[256 + t] + bh[256 + t];
            const float go  = gg[512 + t] + bh[512 + t] + Ds[g][1][t];
            const float gu  = gg[768 + t] + bh[768 + t] + Ds[g][2][t];
            float c = sigf(gi) * tanhf(gu);
            #pragma unroll
            for (int k = 0; k < 4; k++)
                if (cm[g][k] != 0.f)
                    c = fmaf(sigf(gfb + Ds[g][3 + k][t]),
                             Cb[(long)ci[g][k] * HDIM + t], c);
            const float h = sigf(go) * tanhf(c);
            Hb[(long)n * HDIM + t] = h;
            Cb[(long)n * HDIM + t] = c;
            if (do_out && n == 0) hroot[t] = h;
        }
    }

    // ---- root logits + log_softmax (only on the M==1 dispatch) -------------
    if (do_out) {
        __syncthreads();
        const int o    = t >> 6;
        const int lane = t & 63;
        float s = 0.f;
        for (int jj = lane; jj < HDIM; jj += 64)
            s = fmaf(Wout[o * HDIM + jj], hroot[jj], s);
        #pragma unroll
        for (int off = 32; off > 0; off >>= 1)
            s += __shfl_down(s, off, 64);
        if (lane == 0) logits[o] = s + bout[o];
        __syncthreads();
        if (t == 0) {
            float m = logits[0];
            #pragma unroll
            for (int i = 1; i < 4; i++) m = fmaxf(m, logits[i]);
            float se = 0.f;
            #pragma unroll
            for (int i = 0; i < 4; i++) se += __expf(logits[i] - m);
            const float lse = m + __logf(se);
            #pragma unroll
            for (int i = 0; i < 4; i++) out[i] = logits[i] - lse;
        }
    }
}

extern "C" void kernel_launch(void* const* d_in, const int* in_sizes, int n_in,
                              void* d_out, int out_size, void* d_ws, size_t ws_size,
                              hipStream_t stream)
{
    const int*   xs         = (const int*)  d_in[0];
    const int*   child_idx  = (const int*)  d_in[1];
    const float* child_mask = (const float*)d_in[2];
    const float* emb        = (const float*)d_in[3];
    const float* Wx         = (const float*)d_in[4];
    const float* bx         = (const float*)d_in[5];
    const float* Wh         = (const float*)d_in[6];
    const float* bh         = (const float*)d_in[7];
    const float* Wout       = (const float*)d_in[8];
    const float* bout       = (const float*)d_in[9];
    float* out = (float*)d_out;

    float* gxb = (float*)d_ws;
    float* Hb  = gxb + (size_t)N_NODES * GXC;
    float* Cb  = Hb  + (size_t)N_NODES * HDIM;

    gx_gemm<<<dim3(GXC / 64, N_NODES / 64), 256, 0, stream>>>(xs, emb, Wx, bx, gxb);
    leaf_kernel<<<N_NODES - LEAF_FIRST, 256, 0, stream>>>(gxb, bh, Hb, Cb);

    const int pf[7] = {1365, 341, 85, 21, 5, 1, 0};
    const int pc[7] = { 683, 1024, 256, 64, 16, 4, 1};
    for (int p = 0; p < 7; p++) {
        const int grid = (pc[p] + 1) / 2;
        level_fused<<<grid, 256, 0, stream>>>(pf[p], pc[p], (p == 6) ? 1 : 0,
                                              gxb, child_idx, child_mask, Wh, bh,
                                              Hb, Cb, Wout, bout, out);
    }
}

// Round 3
// 405.924 us; speedup vs baseline: 6.5680x; 1.0324x over previous
//
#include <hip/hip_runtime.h>

// ChildSumTreeLSTM on a static 4-ary heap tree.
// N=8192, H=256, D=300, K=4, OUT=4. Leaves = 2048..8191. Internal 0..2047 in 7 levels.
// Workspace: gx [8192][1024] f32, Hb [8192][256] f32, Cb [8192][256] f32.
// D (level-GEMM scratch, <=7.3 MB) aliases gx rows 2048.. (dead after leaf_kernel).
//
// Structure (12 dispatches):
//   1. gx_gemm      — skips dead leaf-f tiles (rows>=2048, cols 256..511 never read)
//   2. leaf_kernel
//   3-8.  big levels p=0..2 (M=683,1024,256): level_gemm + level_pointwise
//         (tiled 64x64 GEMM, W shared across 64 nodes via LDS — W L2 traffic
//          28MB vs 512MB for the fused-GEMV form; measured round 2 regression)
//   9-12. tail levels (M=64,16,4,1): level_fused GEMV (1 dispatch/level,
//         out folded into the root dispatch). Launch overhead ~10us/dispatch
//         dominates these levels; this halves their dispatch count.
// NO cross-block sync anywhere (grid barriers cost ~170us each on the
// non-coherent XCD L2s — measured round 1).

#define N_NODES 8192
#define HDIM 256
#define DDIM 300
#define GXC 1024
#define LEAF_FIRST 2048
#define WH_STRIDE 65536   // 256*256

__device__ __forceinline__ float sigf(float x) { return 1.0f / (1.0f + __expf(-x)); }

// ---------- Kernel 1: gx[n][c] = emb[xs[n]] · Wx[c] + bx[c]  (64x64 tile) ----
__global__ __launch_bounds__(256) void gx_gemm(
    const int* __restrict__ xs, const float* __restrict__ emb,
    const float* __restrict__ Wx, const float* __restrict__ bx,
    float* __restrict__ gx)
{
    const int n0 = blockIdx.y * 64;
    const int c0 = blockIdx.x * 64;
    // Leaf rows' f-gate columns (256..511) are never read downstream: skip.
    if (n0 >= LEAF_FIRST && c0 >= 256 && c0 < 512) return;

    __shared__ __align__(16) float As[16][68];
    __shared__ __align__(16) float Bs[16][68];
    const int tid  = threadIdx.x;
    const int sr   = tid >> 2;
    const int sk   = (tid & 3) << 2;
    const int trow = (tid >> 4) << 2;
    const int tcol = (tid & 15) << 2;

    const long arow = (long)xs[n0 + sr] * DDIM;
    const long brow = (long)(c0 + sr) * DDIM;

    float acc[4][4] = {};

    for (int k0 = 0; k0 < DDIM; k0 += 16) {
        float4 av, bv;
        if (k0 + sk < DDIM) {
            av = *(const float4*)(emb + arow + k0 + sk);
            bv = *(const float4*)(Wx  + brow + k0 + sk);
        } else {
            av = make_float4(0.f, 0.f, 0.f, 0.f);
            bv = make_float4(0.f, 0.f, 0.f, 0.f);
        }
        __syncthreads();
        As[sk+0][sr] = av.x; As[sk+1][sr] = av.y; As[sk+2][sr] = av.z; As[sk+3][sr] = av.w;
        Bs[sk+0][sr] = bv.x; Bs[sk+1][sr] = bv.y; Bs[sk+2][sr] = bv.z; Bs[sk+3][sr] = bv.w;
        __syncthreads();
        #pragma unroll
        for (int k = 0; k < 16; k++) {
            float4 a = *(const float4*)&As[k][trow];
            float4 b = *(const float4*)&Bs[k][tcol];
            float avv[4] = {a.x, a.y, a.z, a.w};
            float bvv[4] = {b.x, b.y, b.z, b.w};
            #pragma unroll
            for (int i = 0; i < 4; i++)
                #pragma unroll
                for (int j = 0; j < 4; j++)
                    acc[i][j] = fmaf(avv[i], bvv[j], acc[i][j]);
        }
    }

    #pragma unroll
    for (int i = 0; i < 4; i++) {
        const int col = c0 + tcol;
        float4 r;
        r.x = acc[i][0] + bx[col + 0];
        r.y = acc[i][1] + bx[col + 1];
        r.z = acc[i][2] + bx[col + 2];
        r.w = acc[i][3] + bx[col + 3];
        *(float4*)(gx + (long)(n0 + trow + i) * GXC + col) = r;
    }
}

// ---------- Kernel 2: leaves — pure elementwise -----------------------------
__global__ __launch_bounds__(256) void leaf_kernel(
    const float* __restrict__ gx, const float* __restrict__ bh,
    float* __restrict__ Hb, float* __restrict__ Cb)
{
    const int node = LEAF_FIRST + blockIdx.x;
    const int t = threadIdx.x;
    const float* g = gx + (long)node * GXC;
    const float gi = g[t]       + bh[t];
    const float go = g[512 + t] + bh[512 + t];
    const float gu = g[768 + t] + bh[768 + t];
    const float c  = sigf(gi) * tanhf(gu);
    const float h  = sigf(go) * tanhf(c);
    Hb[(long)node * HDIM + t] = h;
    Cb[(long)node * HDIM + t] = c;
}

// ---------- Kernel 3: per-level GEMM  D[sec][nl][r] = Wh_g[r,:]·X[nl,:] ------
// blockIdx.y = sec: 0=i (X=hs), 1=o (X=hs), 2=u (X=hs), 3..6=f child c (X=h_c)
// blockIdx.x = 64-col tile over nodes; blockIdx.z = 64-row tile (4 of them).
__global__ __launch_bounds__(256) void level_gemm(
    int first, int M, const float* __restrict__ Hb,
    const int* __restrict__ child_idx, const float* __restrict__ child_mask,
    const float* __restrict__ Wh, float* __restrict__ D)
{
    __shared__ __align__(16) float Xs[16][68];
    __shared__ __align__(16) float Ws[16][68];
    const int tid  = threadIdx.x;
    const int sec  = blockIdx.y;
    const int c0   = blockIdx.x * 64;
    const int r0   = blockIdx.z * 64;
    const int sr   = tid >> 2;
    const int sk   = (tid & 3) << 2;
    const int trow = (tid >> 4) << 2;
    const int tcol = (tid & 15) << 2;

    const float* Wg;
    if      (sec == 0) Wg = Wh;                  // i
    else if (sec == 1) Wg = Wh + 2 * WH_STRIDE;  // o
    else if (sec == 2) Wg = Wh + 3 * WH_STRIDE;  // u
    else               Wg = Wh + 1 * WH_STRIDE;  // f

    const int  nl    = c0 + sr;
    const bool valid = nl < M;
    int   ci[4];
    float cm[4] = {0.f, 0.f, 0.f, 0.f};
    if (valid) {
        const int n = first + nl;
        if (sec < 3) {
            #pragma unroll
            for (int k = 0; k < 4; k++) {
                ci[k] = child_idx[n * 4 + k];
                cm[k] = child_mask[n * 4 + k];
            }
        } else {
            ci[0] = child_idx[n * 4 + (sec - 3)];
            cm[0] = child_mask[n * 4 + (sec - 3)];
        }
    }
    const long wrow = (long)(r0 + sr) * HDIM;

    float acc[4][4] = {};

    for (int k0 = 0; k0 < HDIM; k0 += 16) {
        float4 xv = make_float4(0.f, 0.f, 0.f, 0.f);
        if (valid) {
            if (sec < 3) {
                #pragma unroll
                for (int k = 0; k < 4; k++)
                    if (cm[k] != 0.f) {
                        const float4 hv = *(const float4*)(Hb + ci[k] * HDIM + k0 + sk);
                        xv.x += hv.x; xv.y += hv.y; xv.z += hv.z; xv.w += hv.w;
                    }
            } else if (cm[0] != 0.f) {
                xv = *(const float4*)(Hb + ci[0] * HDIM + k0 + sk);
            }
        }
        const float4 wv = *(const float4*)(Wg + wrow + k0 + sk);
        __syncthreads();
        Xs[sk+0][sr] = xv.x; Xs[sk+1][sr] = xv.y; Xs[sk+2][sr] = xv.z; Xs[sk+3][sr] = xv.w;
        Ws[sk+0][sr] = wv.x; Ws[sk+1][sr] = wv.y; Ws[sk+2][sr] = wv.z; Ws[sk+3][sr] = wv.w;
        __syncthreads();
        #pragma unroll
        for (int k = 0; k < 16; k++) {
            float4 a = *(const float4*)&Ws[k][trow];
            float4 b = *(const float4*)&Xs[k][tcol];
            float avv[4] = {a.x, a.y, a.z, a.w};
            float bvv[4] = {b.x, b.y, b.z, b.w};
            #pragma unroll
            for (int i = 0; i < 4; i++)
                #pragma unroll
                for (int j = 0; j < 4; j++)
                    acc[i][j] = fmaf(avv[i], bvv[j], acc[i][j]);
        }
    }

    #pragma unroll
    for (int j = 0; j < 4; j++) {
        const int col = c0 + tcol + j;
        if (col < M) {
            float4 r;
            r.x = acc[0][j]; r.y = acc[1][j]; r.z = acc[2][j]; r.w = acc[3][j];
            *(float4*)(D + ((long)(sec * M + col)) * HDIM + r0 + trow) = r;
        }
    }
}

// ---------- Kernel 4: per-level pointwise — combine D + gx -> h, c ----------
__global__ __launch_bounds__(256) void level_pointwise(
    int first, int M, const float* __restrict__ gx, const float* __restrict__ D,
    const int* __restrict__ child_idx, const float* __restrict__ child_mask,
    const float* __restrict__ bh, float* __restrict__ Hb, float* __restrict__ Cb)
{
    const int nl = blockIdx.x;
    const int n  = first + nl;
    const int t  = threadIdx.x;
    const float di  = D[((long)(0 * M + nl)) * HDIM + t];
    const float dO  = D[((long)(1 * M + nl)) * HDIM + t];
    const float du  = D[((long)(2 * M + nl)) * HDIM + t];
    const float* g = gx + (long)n * GXC;
    const float gi  = g[t]       + bh[t]       + di;
    const float gfb = g[256 + t] + bh[256 + t];
    const float go  = g[512 + t] + bh[512 + t] + dO;
    const float gu  = g[768 + t] + bh[768 + t] + du;

    float c = sigf(gi) * tanhf(gu);
    #pragma unroll
    for (int k = 0; k < 4; k++) {
        const float m = child_mask[n * 4 + k];
        if (m != 0.f) {
            const float df = D[((long)((3 + k) * M + nl)) * HDIM + t];
            const float cc = Cb[(long)child_idx[n * 4 + k] * HDIM + t];
            c = fmaf(sigf(gfb + df), cc, c);
        }
    }
    const float h = sigf(go) * tanhf(c);
    Hb[(long)n * HDIM + t] = h;
    Cb[(long)n * HDIM + t] = c;
}

// ---------- Kernel 5: fused tail-level kernel (GEMV + pointwise) ------------
// One block = 2 nodes; quad q owns output row r = rb*64+q, lane j covers 4 k's.
// Only used for M <= 64 (Wh L2 traffic = blocks x 1MB — cheap for small M,
// ruinous for big M; measured round 2).
__global__ __launch_bounds__(256) void level_fused(
    int first, int M, int do_out,
    const float* __restrict__ gx, const int* __restrict__ child_idx,
    const float* __restrict__ child_mask, const float* __restrict__ Wh,
    const float* __restrict__ bh, float* __restrict__ Hb, float* __restrict__ Cb,
    const float* __restrict__ Wout, const float* __restrict__ bout,
    float* __restrict__ out)
{
    __shared__ __align__(16) float Xs[2][5][HDIM];   // [g][0]=hs, [g][1+ch]=h_child
    __shared__ __align__(16) float Ds[2][7][HDIM];   // GEMV results (i,o,u,f0..f3)
    __shared__ float hroot[HDIM];
    __shared__ float logits[4];

    const int t   = threadIdx.x;
    const int q   = t >> 2;       // quad 0..63
    const int j   = t & 3;        // k-lane within quad
    const int nl0 = blockIdx.x * 2;

    int   ci[2][4];
    float cm[2][4];
    #pragma unroll
    for (int g = 0; g < 2; g++) {
        const int nl = nl0 + g;
        float s = 0.f;
        if (nl < M) {
            const int n = first + nl;
            #pragma unroll
            for (int k = 0; k < 4; k++) {
                ci[g][k] = child_idx[n * 4 + k];
                cm[g][k] = child_mask[n * 4 + k];
                float v = 0.f;
                if (cm[g][k] != 0.f) v = Hb[(long)ci[g][k] * HDIM + t];
                Xs[g][1 + k][t] = v;
                s += v;
            }
        } else {
            #pragma unroll
            for (int k = 0; k < 4; k++) { ci[g][k] = 0; cm[g][k] = 0.f; Xs[g][1 + k][t] = 0.f; }
        }
        Xs[g][0][t] = s;
    }
    __syncthreads();

    float acc[4][2][7];
    #pragma unroll
    for (int a = 0; a < 4; a++)
        #pragma unroll
        for (int b = 0; b < 2; b++)
            #pragma unroll
            for (int c = 0; c < 7; c++) acc[a][b][c] = 0.f;

    const float* __restrict__ Wi = Wh;                   // gate order in Wh: i,f,o,u
    const float* __restrict__ Wf = Wh + WH_STRIDE;
    const float* __restrict__ Wo = Wh + 2 * WH_STRIDE;
    const float* __restrict__ Wu = Wh + 3 * WH_STRIDE;
    const int kj = j << 2;

    long ro[4];
    #pragma unroll
    for (int rb = 0; rb < 4; rb++) ro[rb] = (long)(rb * 64 + q) * HDIM + kj;

    #pragma unroll 4
    for (int k4 = 0; k4 < 16; k4++) {
        const int kk = (k4 << 4) + kj;
        float4 xsv[2], xcv[2][4];
        #pragma unroll
        for (int g = 0; g < 2; g++) {
            xsv[g] = *(const float4*)&Xs[g][0][kk];
            #pragma unroll
            for (int ch = 0; ch < 4; ch++)
                xcv[g][ch] = *(const float4*)&Xs[g][1 + ch][kk];
        }
        #pragma unroll
        for (int rb = 0; rb < 4; rb++) {
            const long o4 = ro[rb] + (k4 << 4);
            const float4 wi = *(const float4*)(Wi + o4);
            const float4 wo = *(const float4*)(Wo + o4);
            const float4 wu = *(const float4*)(Wu + o4);
            const float4 wf = *(const float4*)(Wf + o4);
            #pragma unroll
            for (int g = 0; g < 2; g++) {
                acc[rb][g][0] += wi.x*xsv[g].x + wi.y*xsv[g].y + wi.z*xsv[g].z + wi.w*xsv[g].w;
                acc[rb][g][1] += wo.x*xsv[g].x + wo.y*xsv[g].y + wo.z*xsv[g].z + wo.w*xsv[g].w;
                acc[rb][g][2] += wu.x*xsv[g].x + wu.y*xsv[g].y + wu.z*xsv[g].z + wu.w*xsv[g].w;
                #pragma unroll
                for (int ch = 0; ch < 4; ch++)
                    acc[rb][g][3 + ch] += wf.x*xcv[g][ch].x + wf.y*xcv[g][ch].y
                                        + wf.z*xcv[g][ch].z + wf.w*xcv[g][ch].w;
            }
        }
    }

    #pragma unroll
    for (int rb = 0; rb < 4; rb++)
        #pragma unroll
        for (int g = 0; g < 2; g++)
            #pragma unroll
            for (int s7 = 0; s7 < 7; s7++) {
                float v = acc[rb][g][s7];
                v += __shfl_xor(v, 1, 64);
                v += __shfl_xor(v, 2, 64);
                if (j == 0) Ds[g][s7][rb * 64 + q] = v;
            }
    __syncthreads();

    #pragma unroll
    for (int g = 0; g < 2; g++) {
        const int nl = nl0 + g;
        if (nl < M) {
            const int n = first + nl;
            const float* gg = gx + (long)n * GXC;
            const float gi  = gg[t]       + bh[t]       + Ds[g][0][t];
            const float gfb = gg[256 + t] + bh[256 + t];
            const float go  = gg[512 + t] + bh[512 + t] + Ds[g][1][t];
            const float gu  = gg[768 + t] + bh[768 + t] + Ds[g][2][t];
            float c = sigf(gi) * tanhf(gu);
            #pragma unroll
            for (int k = 0; k < 4; k++)
                if (cm[g][k] != 0.f)
                    c = fmaf(sigf(gfb + Ds[g][3 + k][t]),
                             Cb[(long)ci[g][k] * HDIM + t], c);
            const float h = sigf(go) * tanhf(c);
            Hb[(long)n * HDIM + t] = h;
            Cb[(long)n * HDIM + t] = c;
            if (do_out && n == 0) hroot[t] = h;
        }
    }

    if (do_out) {
        __syncthreads();
        const int o    = t >> 6;
        const int lane = t & 63;
        float s = 0.f;
        for (int jj = lane; jj < HDIM; jj += 64)
            s = fmaf(Wout[o * HDIM + jj], hroot[jj], s);
        #pragma unroll
        for (int off = 32; off > 0; off >>= 1)
            s += __shfl_down(s, off, 64);
        if (lane == 0) logits[o] = s + bout[o];
        __syncthreads();
        if (t == 0) {
            float m = logits[0];
            #pragma unroll
            for (int i = 1; i < 4; i++) m = fmaxf(m, logits[i]);
            float se = 0.f;
            #pragma unroll
            for (int i = 0; i < 4; i++) se += __expf(logits[i] - m);
            const float lse = m + __logf(se);
            #pragma unroll
            for (int i = 0; i < 4; i++) out[i] = logits[i] - lse;
        }
    }
}

extern "C" void kernel_launch(void* const* d_in, const int* in_sizes, int n_in,
                              void* d_out, int out_size, void* d_ws, size_t ws_size,
                              hipStream_t stream)
{
    const int*   xs         = (const int*)  d_in[0];
    const int*   child_idx  = (const int*)  d_in[1];
    const float* child_mask = (const float*)d_in[2];
    const float* emb        = (const float*)d_in[3];
    const float* Wx         = (const float*)d_in[4];
    const float* bx         = (const float*)d_in[5];
    const float* Wh         = (const float*)d_in[6];
    const float* bh         = (const float*)d_in[7];
    const float* Wout       = (const float*)d_in[8];
    const float* bout       = (const float*)d_in[9];
    float* out = (float*)d_out;

    float* gxb = (float*)d_ws;
    float* Hb  = gxb + (size_t)N_NODES * GXC;
    float* Cb  = Hb  + (size_t)N_NODES * HDIM;
    // D aliases the gx rows of leaf nodes (dead after leaf_kernel).
    // Max size: 7*1024*256 floats = 7.3 MB -> gx rows 2048..~3840.
    float* Dbuf = gxb + (size_t)LEAF_FIRST * GXC;

    gx_gemm<<<dim3(GXC / 64, N_NODES / 64), 256, 0, stream>>>(xs, emb, Wx, bx, gxb);
    leaf_kernel<<<N_NODES - LEAF_FIRST, 256, 0, stream>>>(gxb, bh, Hb, Cb);

    // Big levels: tiled GEMM + pointwise (2 dispatches each).
    const int pfb[3] = {1365, 341, 85};
    const int pcb[3] = { 683, 1024, 256};
    for (int p = 0; p < 3; p++) {
        const int M = pcb[p];
        dim3 grid((M + 63) / 64, 7, 4);
        level_gemm<<<grid, 256, 0, stream>>>(pfb[p], M, Hb, child_idx, child_mask,
                                             Wh, Dbuf);
        level_pointwise<<<M, 256, 0, stream>>>(pfb[p], M, gxb, Dbuf, child_idx,
                                               child_mask, bh, Hb, Cb);
    }

    // Tail levels: fused GEMV+pointwise (1 dispatch each, out folded into root).
    const int pft[4] = {21, 5, 1, 0};
    const int pct[4] = {64, 16, 4, 1};
    for (int p = 0; p < 4; p++) {
        const int grid = (pct[p] + 1) / 2;
        level_fused<<<grid, 256, 0, stream>>>(pft[p], pct[p], (p == 3) ? 1 : 0,
                                              gxb, child_idx, child_mask, Wh, bh,
                                              Hb, Cb, Wout, bout, out);
    }
}